// Round 2
// baseline (167.654 us; speedup 1.0000x reference)
//
#include <hip/hip_runtime.h>
#include <hip/hip_bf16.h>
#include <math.h>

#define EPSF 1e-6f

__device__ __forceinline__ float wave_sum64(float v) {
#pragma unroll
    for (int off = 32; off > 0; off >>= 1) v += __shfl_xor(v, off, 64);
    return v;
}

// posenc element e in [0,126): [plucker(6) | sin(2^j * x_i) j=0..9 | sin(2^j*x_i + pi/2) j=0..9]
// flat layout: net[6 + j*6 + i], j in 0..19
__device__ __forceinline__ float posenc_elem(const float* pl, int e) {
    if (e < 6) return pl[e];
    int t = e - 6;
    int j = t / 6;
    int i = t - j * 6;
    int jm = (j < 10) ? j : (j - 10);
    float arg = pl[i] * (float)(1 << jm);
    if (j >= 10) arg += 1.5707963705062866f;  // f32(pi/2): matches ref's f32 add
    return sinf(arg);
}

// ws layout (f32):
//   [0 .. K*8064)                 : W0_T[k][m*64+n]   (n_in=126)
//   [offW .. offW + K*7*4096)     : Wl_T[k][l-1][m*64+n]
//   [offB .. offB + K*8*64)       : b_eff[k][l][n]
__global__ __launch_bounds__(256) void precompute_kernel(
    const float* __restrict__ latent_tokens, const float* __restrict__ token_embeddings,
    const float* __restrict__ h_W0, const float* __restrict__ h_b0,
    const float* __restrict__ h_ln_s0, const float* __restrict__ h_ln_b0,
    const float* __restrict__ w_W0, const float* __restrict__ w_b0,
    const float* __restrict__ bb_W0, const float* __restrict__ bb_b0,
    const float* __restrict__ h_W, const float* __restrict__ h_b,
    const float* __restrict__ h_ln_s, const float* __restrict__ h_ln_b,
    const float* __restrict__ w_W, const float* __restrict__ w_b,
    const float* __restrict__ bb_W, const float* __restrict__ bb_b,
    float* __restrict__ ws, int offW, int offB)
{
    const int s = blockIdx.x;   // column-slice 0..15
    const int l = blockIdx.y;   // 0..7
    const int k = blockIdx.z;   // 0..K-1
    const int tid = threadIdx.x;

    __shared__ float s_chunk[128];
    __shared__ float s_h[64];

    if (tid < 128) {
        s_chunk[tid] = (tid < 64) ? latent_tokens[(k * 8 + l) * 64 + tid]
                                  : token_embeddings[l * 64 + (tid - 64)];
    }
    __syncthreads();

    const float* hW  = (l == 0) ? h_W0    : h_W    + (size_t)(l - 1) * 128 * 64;
    const float* hb  = (l == 0) ? h_b0    : h_b    + (l - 1) * 64;
    const float* hls = (l == 0) ? h_ln_s0 : h_ln_s + (l - 1) * 64;
    const float* hlb = (l == 0) ? h_ln_b0 : h_ln_b + (l - 1) * 64;

    if (tid < 64) {  // wave 0 exactly (redundant per slice-block; tiny)
        float acc = hb[tid];
#pragma unroll 4
        for (int m = 0; m < 128; m++) acc += s_chunk[m] * hW[m * 64 + tid];
        float mu  = wave_sum64(acc) * (1.0f / 64.0f);
        float d   = acc - mu;
        float var = wave_sum64(d * d) * (1.0f / 64.0f);
        float y   = d * rsqrtf(var + EPSF) * hls[tid] + hlb[tid];
        s_h[tid]  = fmaxf(y, 0.0f);
    }
    __syncthreads();

    const int n_in  = (l == 0) ? 126 : 64;
    const int nflat = 64 * n_in;
    const int slice = nflat / 16;        // 504 or 256, both exact
    const int o0 = s * slice;
    const float* wW = (l == 0) ? w_W0 : w_W + (size_t)(l - 1) * 64 * 4096;
    const float* wb = (l == 0) ? w_b0 : w_b + (size_t)(l - 1) * 4096;
    float* Wt = (l == 0) ? ws + (size_t)k * 8064
                         : ws + offW + ((size_t)k * 7 + (l - 1)) * 4096;

    for (int o = o0 + tid; o < o0 + slice; o += 256) {
        float acc = wb[o];
#pragma unroll 8
        for (int j = 0; j < 64; j++) acc += s_h[j] * wW[j * nflat + o];
        int n = o / n_in;
        int m = o - n * n_in;
        Wt[m * 64 + n] = acc;   // transposed: forward reads coalesce over n=lane
    }

    if (s == 0 && tid < 64) {
        const float* bW  = (l == 0) ? bb_W0 : bb_W + (size_t)(l - 1) * 64 * 64;
        const float* bb_ = (l == 0) ? bb_b0 : bb_b + (l - 1) * 64;
        float acc = bb_[tid];
#pragma unroll 8
        for (int j = 0; j < 64; j++) acc += s_h[j] * bW[j * 64 + tid];
        ws[offB + (k * 8 + l) * 64 + tid] = acc;
    }
}

// one wave per ray; lane n = neuron n; block = 4 waves = 4 rays
__global__ __launch_bounds__(256) void forward_kernel(
    const float* __restrict__ rays,
    const float* __restrict__ ln_s0, const float* __restrict__ ln_b0,
    const float* __restrict__ ln_s, const float* __restrict__ ln_b,
    const float* __restrict__ rgb_W, const float* __restrict__ rgb_b,
    const float* __restrict__ ws, int offW, int offB,
    float* __restrict__ out, int K, int P)
{
    const int warp = threadIdx.x >> 6;
    const int lane = threadIdx.x & 63;
    int r = blockIdx.x * 4 + warp;
    const int total = K * P;
    const bool active = (r < total);
    if (!active) r = 0;                 // keep loads in-bounds; all threads hit barriers
    const int k = r / P;

    __shared__ float s_net[4][128];

    float o0 = rays[r * 6 + 0], o1 = rays[r * 6 + 1], o2 = rays[r * 6 + 2];
    float d0 = rays[r * 6 + 3], d1 = rays[r * 6 + 4], d2 = rays[r * 6 + 5];
    float pl[6];
    pl[0] = d0; pl[1] = d1; pl[2] = d2;
    pl[3] = o1 * d2 - o2 * d1;
    pl[4] = o2 * d0 - o0 * d2;
    pl[5] = o0 * d1 - o1 * d0;

    // posenc: 126 values, 2 per lane (zero-pad 126..127)
    s_net[warp][lane] = posenc_elem(pl, lane);
    s_net[warp][lane + 64] = (lane + 64 < 126) ? posenc_elem(pl, lane + 64) : 0.0f;
    __syncthreads();

    // layer 0: n_in = 126
    const float* W0 = ws + (size_t)k * 8064;
    float acc = ws[offB + (k * 8 + 0) * 64 + lane];
#pragma unroll 6
    for (int m = 0; m < 126; m++) acc += s_net[warp][m] * W0[m * 64 + lane];
    {
        float mu  = wave_sum64(acc) * (1.0f / 64.0f);
        float d   = acc - mu;
        float var = wave_sum64(d * d) * (1.0f / 64.0f);
        acc = fmaxf(d * rsqrtf(var + EPSF) * ln_s0[lane] + ln_b0[lane], 0.0f);
    }

    // layers 1..7: n_in = 64
    for (int l = 1; l < 8; l++) {
        __syncthreads();                 // WAR vs previous reads is wave-local, but be safe
        s_net[warp][lane] = acc;
        __syncthreads();
        const float* Wl = ws + offW + ((size_t)k * 7 + (l - 1)) * 4096;
        float a = ws[offB + (k * 8 + l) * 64 + lane];
#pragma unroll 8
        for (int m = 0; m < 64; m++) a += s_net[warp][m] * Wl[m * 64 + lane];
        float mu  = wave_sum64(a) * (1.0f / 64.0f);
        float d   = a - mu;
        float var = wave_sum64(d * d) * (1.0f / 64.0f);
        acc = fmaxf(d * rsqrtf(var + EPSF) * ln_s[(l - 1) * 64 + lane]
                    + ln_b[(l - 1) * 64 + lane], 0.0f);
    }

    // rgb head: rgb_W is (64,3) row-major
    float c0 = wave_sum64(acc * rgb_W[lane * 3 + 0]);
    float c1 = wave_sum64(acc * rgb_W[lane * 3 + 1]);
    float c2 = wave_sum64(acc * rgb_W[lane * 3 + 2]);
    if (active && lane == 0) {
        out[r * 3 + 0] = 1.0f / (1.0f + expf(-(c0 + rgb_b[0])));
        out[r * 3 + 1] = 1.0f / (1.0f + expf(-(c1 + rgb_b[1])));
        out[r * 3 + 2] = 1.0f / (1.0f + expf(-(c2 + rgb_b[2])));
    }
}

extern "C" void kernel_launch(void* const* d_in, const int* in_sizes, int n_in,
                              void* d_out, int out_size, void* d_ws, size_t ws_size,
                              hipStream_t stream) {
    const float* rays    = (const float*)d_in[0];
    const float* latent  = (const float*)d_in[1];
    const float* tok_emb = (const float*)d_in[2];
    const float* h_W0    = (const float*)d_in[3];
    const float* h_b0    = (const float*)d_in[4];
    const float* h_ln_s0 = (const float*)d_in[5];
    const float* h_ln_b0 = (const float*)d_in[6];
    const float* w_W0    = (const float*)d_in[7];
    const float* w_b0    = (const float*)d_in[8];
    const float* bb_W0   = (const float*)d_in[9];
    const float* bb_b0   = (const float*)d_in[10];
    const float* ln_s0   = (const float*)d_in[11];
    const float* ln_b0   = (const float*)d_in[12];
    const float* h_W     = (const float*)d_in[13];
    const float* h_b     = (const float*)d_in[14];
    const float* h_ln_s  = (const float*)d_in[15];
    const float* h_ln_b  = (const float*)d_in[16];
    const float* w_W     = (const float*)d_in[17];
    const float* w_b     = (const float*)d_in[18];
    const float* bb_W    = (const float*)d_in[19];
    const float* bb_b    = (const float*)d_in[20];
    const float* ln_s    = (const float*)d_in[21];
    const float* ln_b    = (const float*)d_in[22];
    const float* rgb_W   = (const float*)d_in[23];
    const float* rgb_b   = (const float*)d_in[24];
    float* out = (float*)d_out;

    const int K = in_sizes[1] / (8 * 64);      // latent_tokens (K,8,64)
    const int P = in_sizes[0] / (6 * K);       // rays (K,P,6)
    const int offW = K * 8064;                 // f32 elements
    const int offB = offW + K * 7 * 4096;

    float* ws = (float*)d_ws;

    dim3 pgrid(16, 8, K);
    precompute_kernel<<<pgrid, 256, 0, stream>>>(
        latent, tok_emb, h_W0, h_b0, h_ln_s0, h_ln_b0, w_W0, w_b0, bb_W0, bb_b0,
        h_W, h_b, h_ln_s, h_ln_b, w_W, w_b, bb_W, bb_b, ws, offW, offB);

    const int total = K * P;
    const int blocks = (total + 3) / 4;
    forward_kernel<<<blocks, 256, 0, stream>>>(
        rays, ln_s0, ln_b0, ln_s, ln_b, rgb_W, rgb_b,
        ws, offW, offB, out, K, P);
}

// Round 3
// 159.421 us; speedup vs baseline: 1.0516x; 1.0516x over previous
//
#include <hip/hip_runtime.h>
#include <math.h>

#define EPSF 1e-6f
#define RPW 4   // rays per wave

__device__ __forceinline__ float rl(float v, int srclane) {
    return __uint_as_float(__builtin_amdgcn_readlane(__float_as_uint(v), srclane));
}

__device__ __forceinline__ float wave_sum64(float v) {
#pragma unroll
    for (int off = 32; off > 0; off >>= 1) v += __shfl_xor(v, off, 64);
    return v;
}

__device__ __forceinline__ float ln_relu(float a, float s, float b) {
    float mu  = wave_sum64(a) * (1.0f / 64.0f);
    float d   = a - mu;
    float var = wave_sum64(d * d) * (1.0f / 64.0f);
    return fmaxf(d * rsqrtf(var + EPSF) * s + b, 0.0f);
}

// posenc element e in [0,126): [plucker(6) | sin(2^j*x_i) j=0..9 | sin(2^j*x_i + pi/2) j=0..9]
__device__ __forceinline__ float posenc_elem(const float* pl, int e) {
    if (e < 6) return pl[e];
    int t = e - 6;
    int j = t / 6;
    int i = t - j * 6;
    int jm = (j < 10) ? j : (j - 10);
    float arg = pl[i] * (float)(1 << jm);
    if (j >= 10) arg += 1.5707963705062866f;  // f32(pi/2), matches ref
    return sinf(arg);
}

// ws layout (f32):
//   [0 .. K*8192)              : W0[k][n*128+m]  natural layout, rows padded 126->128 (pad=0)
//   [offW .. offW+K*7*4096)    : Wl[k][l-1][n*64+m]  natural layout
//   [offB .. offB+K*8*64)      : b_eff[k][l][n]
__global__ __launch_bounds__(256) void precompute_kernel(
    const float* __restrict__ latent_tokens, const float* __restrict__ token_embeddings,
    const float* __restrict__ h_W0, const float* __restrict__ h_b0,
    const float* __restrict__ h_ln_s0, const float* __restrict__ h_ln_b0,
    const float* __restrict__ w_W0, const float* __restrict__ w_b0,
    const float* __restrict__ bb_W0, const float* __restrict__ bb_b0,
    const float* __restrict__ h_W, const float* __restrict__ h_b,
    const float* __restrict__ h_ln_s, const float* __restrict__ h_ln_b,
    const float* __restrict__ w_W, const float* __restrict__ w_b,
    const float* __restrict__ bb_W, const float* __restrict__ bb_b,
    float* __restrict__ ws, int offW, int offB)
{
    const int s = blockIdx.x;   // column-slice 0..15
    const int l = blockIdx.y;   // 0..7
    const int k = blockIdx.z;   // 0..K-1
    const int tid = threadIdx.x;

    __shared__ float s_chunk[128];
    __shared__ float s_h[64];

    if (tid < 128) {
        s_chunk[tid] = (tid < 64) ? latent_tokens[(k * 8 + l) * 64 + tid]
                                  : token_embeddings[l * 64 + (tid - 64)];
    }
    __syncthreads();

    const float* hW  = (l == 0) ? h_W0    : h_W    + (size_t)(l - 1) * 128 * 64;
    const float* hb  = (l == 0) ? h_b0    : h_b    + (l - 1) * 64;
    const float* hls = (l == 0) ? h_ln_s0 : h_ln_s + (l - 1) * 64;
    const float* hlb = (l == 0) ? h_ln_b0 : h_ln_b + (l - 1) * 64;

    if (tid < 64) {  // wave 0; deep unroll to keep many loads in flight
        float acc = hb[tid];
#pragma unroll 16
        for (int m = 0; m < 128; m++) acc += s_chunk[m] * hW[m * 64 + tid];
        float mu  = wave_sum64(acc) * (1.0f / 64.0f);
        float d   = acc - mu;
        float var = wave_sum64(d * d) * (1.0f / 64.0f);
        float y   = d * rsqrtf(var + EPSF) * hls[tid] + hlb[tid];
        s_h[tid]  = fmaxf(y, 0.0f);
    }
    __syncthreads();

    const int n_in  = (l == 0) ? 126 : 64;
    const int nflat = 64 * n_in;
    const int slice = nflat / 16;        // 504 or 256, both exact
    const int o0 = s * slice;
    const float* wW = (l == 0) ? w_W0 : w_W + (size_t)(l - 1) * 64 * 4096;
    const float* wb = (l == 0) ? w_b0 : w_b + (size_t)(l - 1) * 4096;
    float* Wt = (l == 0) ? ws + (size_t)k * 8192
                         : ws + offW + ((size_t)k * 7 + (l - 1)) * 4096;

    for (int o = o0 + tid; o < o0 + slice; o += 256) {
        float acc = wb[o];
#pragma unroll 8
        for (int j = 0; j < 64; j++) acc += s_h[j] * wW[j * nflat + o];
        if (l == 0) {
            int n = o / 126;
            int m = o - n * 126;
            Wt[n * 128 + m] = acc;       // natural layout, padded row stride
        } else {
            Wt[o] = acc;                 // natural layout [n][m]
        }
    }

    if (l == 0 && s == 0 && tid < 128) { // zero the row pads (ws is re-poisoned each call)
        Wt[(tid >> 1) * 128 + 126 + (tid & 1)] = 0.0f;
    }

    if (s == 0 && tid < 64) {
        const float* bW  = (l == 0) ? bb_W0 : bb_W + (size_t)(l - 1) * 64 * 64;
        const float* bb_ = (l == 0) ? bb_b0 : bb_b + (l - 1) * 64;
        float acc = bb_[tid];
#pragma unroll 8
        for (int j = 0; j < 64; j++) acc += s_h[j] * bW[j * 64 + tid];
        ws[offB + (k * 8 + l) * 64 + tid] = acc;
    }
}

// one wave handles RPW rays; lane n = neuron n; no LDS, no barriers.
// Weights: each lane loads ITS OWN contiguous row (float4), activations
// broadcast in-register via v_readlane with compile-time lane index.
__global__ __launch_bounds__(256) void forward_kernel(
    const float* __restrict__ rays,
    const float* __restrict__ ln_s0, const float* __restrict__ ln_b0,
    const float* __restrict__ ln_s, const float* __restrict__ ln_b,
    const float* __restrict__ rgb_W, const float* __restrict__ rgb_b,
    const float* __restrict__ ws, int offW, int offB,
    float* __restrict__ out, int K, int P)
{
    const int warp = threadIdx.x >> 6;
    const int lane = threadIdx.x & 63;
    const int total = K * P;
    const int r0 = (blockIdx.x * 4 + warp) * RPW;
    if (r0 >= total) return;            // whole-wave exit; no barriers anywhere
    const int k = r0 / P;               // P % 16 == 0 -> k uniform per wave

    // posenc for RPW rays; ray data addresses are wave-uniform -> scalar loads
    float net0[RPW], net1[RPW];
#pragma unroll
    for (int q = 0; q < RPW; q++) {
        int r = r0 + q; if (r > total - 1) r = total - 1;
        float o0 = rays[r * 6 + 0], o1 = rays[r * 6 + 1], o2 = rays[r * 6 + 2];
        float d0 = rays[r * 6 + 3], d1 = rays[r * 6 + 4], d2 = rays[r * 6 + 5];
        float pl[6];
        pl[0] = d0; pl[1] = d1; pl[2] = d2;
        pl[3] = o1 * d2 - o2 * d1;
        pl[4] = o2 * d0 - o0 * d2;
        pl[5] = o0 * d1 - o1 * d0;
        net0[q] = posenc_elem(pl, lane);
        net1[q] = (lane + 64 < 126) ? posenc_elem(pl, lane + 64) : 0.0f;
    }

    float acc[RPW];

    { // layer 0: n_in = 126 (padded 128); lane's row = W0 + lane*128
        const float4* row = (const float4*)(ws + (size_t)k * 8192 + lane * 128);
        float bia = ws[offB + (k * 8 + 0) * 64 + lane];
#pragma unroll
        for (int q = 0; q < RPW; q++) acc[q] = bia;

        float4 w4[16];
#pragma unroll
        for (int j = 0; j < 16; j++) w4[j] = row[j];        // m = 0..63
#pragma unroll
        for (int m = 0; m < 64; m++) {
            float wm = ((const float*)w4)[m];
#pragma unroll
            for (int q = 0; q < RPW; q++) acc[q] += rl(net0[q], m) * wm;
        }
#pragma unroll
        for (int j = 0; j < 16; j++) w4[j] = row[16 + j];   // m = 64..127 (pads are 0-weighted: net pad=0? pad w=0)
#pragma unroll
        for (int m = 0; m < 64; m++) {
            float wm = ((const float*)w4)[m];
#pragma unroll
            for (int q = 0; q < RPW; q++) acc[q] += rl(net1[q], m) * wm;
        }
        float s = ln_s0[lane], b = ln_b0[lane];
#pragma unroll
        for (int q = 0; q < RPW; q++) acc[q] = ln_relu(acc[q], s, b);
    }

    // layers 1..7: n_in = 64; lane's row = Wl + lane*64
#pragma unroll 1
    for (int l = 1; l < 8; l++) {
        const float4* row = (const float4*)(ws + offW + ((size_t)k * 7 + (l - 1)) * 4096 + lane * 64);
        float bia = ws[offB + (k * 8 + l) * 64 + lane];
        float4 w4[16];
#pragma unroll
        for (int j = 0; j < 16; j++) w4[j] = row[j];
        float na[RPW];
#pragma unroll
        for (int q = 0; q < RPW; q++) na[q] = bia;
#pragma unroll
        for (int m = 0; m < 64; m++) {
            float wm = ((const float*)w4)[m];
#pragma unroll
            for (int q = 0; q < RPW; q++) na[q] += rl(acc[q], m) * wm;
        }
        float s = ln_s[(l - 1) * 64 + lane], b = ln_b[(l - 1) * 64 + lane];
#pragma unroll
        for (int q = 0; q < RPW; q++) acc[q] = ln_relu(na[q], s, b);
    }

    // rgb head: rgb_W is (64,3) row-major
    float w0 = rgb_W[lane * 3 + 0], w1 = rgb_W[lane * 3 + 1], w2 = rgb_W[lane * 3 + 2];
    float b0 = rgb_b[0], b1 = rgb_b[1], b2 = rgb_b[2];
#pragma unroll
    for (int q = 0; q < RPW; q++) {
        float c0 = wave_sum64(acc[q] * w0);
        float c1 = wave_sum64(acc[q] * w1);
        float c2 = wave_sum64(acc[q] * w2);
        if (lane == 0 && r0 + q < total) {
            out[(r0 + q) * 3 + 0] = 1.0f / (1.0f + expf(-(c0 + b0)));
            out[(r0 + q) * 3 + 1] = 1.0f / (1.0f + expf(-(c1 + b1)));
            out[(r0 + q) * 3 + 2] = 1.0f / (1.0f + expf(-(c2 + b2)));
        }
    }
}

extern "C" void kernel_launch(void* const* d_in, const int* in_sizes, int n_in,
                              void* d_out, int out_size, void* d_ws, size_t ws_size,
                              hipStream_t stream) {
    const float* rays    = (const float*)d_in[0];
    const float* latent  = (const float*)d_in[1];
    const float* tok_emb = (const float*)d_in[2];
    const float* h_W0    = (const float*)d_in[3];
    const float* h_b0    = (const float*)d_in[4];
    const float* h_ln_s0 = (const float*)d_in[5];
    const float* h_ln_b0 = (const float*)d_in[6];
    const float* w_W0    = (const float*)d_in[7];
    const float* w_b0    = (const float*)d_in[8];
    const float* bb_W0   = (const float*)d_in[9];
    const float* bb_b0   = (const float*)d_in[10];
    const float* ln_s0   = (const float*)d_in[11];
    const float* ln_b0   = (const float*)d_in[12];
    const float* h_W     = (const float*)d_in[13];
    const float* h_b     = (const float*)d_in[14];
    const float* h_ln_s  = (const float*)d_in[15];
    const float* h_ln_b  = (const float*)d_in[16];
    const float* w_W     = (const float*)d_in[17];
    const float* w_b     = (const float*)d_in[18];
    const float* bb_W    = (const float*)d_in[19];
    const float* bb_b    = (const float*)d_in[20];
    const float* ln_s    = (const float*)d_in[21];
    const float* ln_b    = (const float*)d_in[22];
    const float* rgb_W   = (const float*)d_in[23];
    const float* rgb_b   = (const float*)d_in[24];
    float* out = (float*)d_out;

    const int K = in_sizes[1] / (8 * 64);      // latent_tokens (K,8,64)
    const int P = in_sizes[0] / (6 * K);       // rays (K,P,6)
    const int offW = K * 8192;                 // f32 elements (W0 rows padded to 128)
    const int offB = offW + K * 7 * 4096;

    float* ws = (float*)d_ws;

    dim3 pgrid(16, 8, K);
    precompute_kernel<<<pgrid, 256, 0, stream>>>(
        latent, tok_emb, h_W0, h_b0, h_ln_s0, h_ln_b0, w_W0, w_b0, bb_W0, bb_b0,
        h_W, h_b, h_ln_s, h_ln_b, w_W, w_b, bb_W, bb_b, ws, offW, offB);

    const int total = K * P;
    const int rays_per_block = 4 * RPW;        // 4 waves * RPW
    const int blocks = (total + rays_per_block - 1) / rays_per_block;
    forward_kernel<<<blocks, 256, 0, stream>>>(
        rays, ln_s0, ln_b0, ln_s, ln_b, rgb_W, rgb_b,
        ws, offW, offB, out, K, P);
}

// Round 4
// 157.017 us; speedup vs baseline: 1.0677x; 1.0153x over previous
//
#include <hip/hip_runtime.h>
#include <math.h>

#define EPSF 1e-6f
#define RPW 4   // rays per wave

__device__ __forceinline__ float rl(float v, int srclane) {
    return __uint_as_float(__builtin_amdgcn_readlane(__float_as_uint(v), srclane));
}

__device__ __forceinline__ float wave_sum64(float v) {
#pragma unroll
    for (int off = 32; off > 0; off >>= 1) v += __shfl_xor(v, off, 64);
    return v;
}

// single-pass LN stats: mu and rstd from (sum, sumsq) in ONE 6-step shuffle chain
__device__ __forceinline__ void ln_stats(float a, float& mu, float& rstd) {
    float s1 = a, s2 = a * a;
#pragma unroll
    for (int off = 32; off > 0; off >>= 1) {
        s1 += __shfl_xor(s1, off, 64);
        s2 += __shfl_xor(s2, off, 64);
    }
    mu = s1 * (1.0f / 64.0f);
    float var = fmaxf(s2 * (1.0f / 64.0f) - mu * mu, 0.0f);
    rstd = rsqrtf(var + EPSF);
}

// posenc element e in [0,126): [plucker(6) | sin(2^j*x_i) j=0..9 | sin(2^j*x_i + pi/2) j=0..9]
__device__ __forceinline__ float posenc_elem(const float* pl, int e) {
    if (e < 6) return pl[e];
    int t = e - 6;
    int j = t / 6;
    int i = t - j * 6;
    int jm = (j < 10) ? j : (j - 10);
    float arg = pl[i] * (float)(1 << jm);
    if (j >= 10) arg += 1.5707963705062866f;  // f32(pi/2), matches ref
    return sinf(arg);
}

// ws layout (f32):
//   [0 .. K*8192)              : W0[k][n*128+m]  natural layout, rows padded 126->128 (pad=0)
//   [offW .. offW+K*7*4096)    : Wl[k][l-1][n*64+m]  natural layout
//   [offB .. offB+K*8*64)      : b_eff[k][l][n]
__global__ __launch_bounds__(128, 4) void precompute_kernel(
    const float* __restrict__ latent_tokens, const float* __restrict__ token_embeddings,
    const float* __restrict__ h_W0, const float* __restrict__ h_b0,
    const float* __restrict__ h_ln_s0, const float* __restrict__ h_ln_b0,
    const float* __restrict__ w_W0, const float* __restrict__ w_b0,
    const float* __restrict__ bb_W0, const float* __restrict__ bb_b0,
    const float* __restrict__ h_W, const float* __restrict__ h_b,
    const float* __restrict__ h_ln_s, const float* __restrict__ h_ln_b,
    const float* __restrict__ w_W, const float* __restrict__ w_b,
    const float* __restrict__ bb_W, const float* __restrict__ bb_b,
    float* __restrict__ ws, int offW, int offB)
{
    const int s = blockIdx.x;   // column-slice 0..31
    const int l = blockIdx.y;   // 0..7
    const int k = blockIdx.z;   // 0..K-1
    const int tid = threadIdx.x;

    __shared__ float s_chunk[128];
    __shared__ float s_h[64];

    s_chunk[tid] = (tid < 64) ? latent_tokens[(k * 8 + l) * 64 + tid]
                              : token_embeddings[l * 64 + (tid - 64)];
    __syncthreads();

    const float* hW  = (l == 0) ? h_W0    : h_W    + (size_t)(l - 1) * 128 * 64;
    const float* hb  = (l == 0) ? h_b0    : h_b    + (l - 1) * 64;
    const float* hls = (l == 0) ? h_ln_s0 : h_ln_s + (l - 1) * 64;
    const float* hlb = (l == 0) ? h_ln_b0 : h_ln_b + (l - 1) * 64;

    if (tid < 64) {  // wave 0
        float acc = hb[tid];
#pragma unroll 16
        for (int m = 0; m < 128; m++) acc += s_chunk[m] * hW[m * 64 + tid];
        float mu, rstd;
        ln_stats(acc, mu, rstd);
        float y = (acc - mu) * rstd * hls[tid] + hlb[tid];
        s_h[tid] = fmaxf(y, 0.0f);
    }
    __syncthreads();

    const int n_in  = (l == 0) ? 126 : 64;
    const int nflat = 64 * n_in;
    const int slice = nflat / 32;        // 252 or 128
    const int o0 = s * slice;
    const float* wW = (l == 0) ? w_W0 : w_W + (size_t)(l - 1) * 64 * 4096;
    const float* wb = (l == 0) ? w_b0 : w_b + (size_t)(l - 1) * 4096;
    float* Wt = (l == 0) ? ws + (size_t)k * 8192
                         : ws + offW + ((size_t)k * 7 + (l - 1)) * 4096;

    for (int o = o0 + tid; o < o0 + slice; o += 128) {
        float acc = wb[o];
#pragma unroll 16
        for (int j = 0; j < 64; j++) acc += s_h[j] * wW[j * nflat + o];
        if (l == 0) {
            int n = o / 126;
            int m = o - n * 126;
            Wt[n * 128 + m] = acc;       // natural layout, padded row stride
        } else {
            Wt[o] = acc;                 // natural layout [n][m]
        }
    }

    if (l == 0 && s == 0) {              // zero the row pads (ws re-poisoned per call)
        Wt[(tid >> 1) * 128 + 126 + (tid & 1)] = 0.0f;
    }

    if (s == 0 && tid < 64) {
        const float* bW  = (l == 0) ? bb_W0 : bb_W + (size_t)(l - 1) * 64 * 64;
        const float* bb_ = (l == 0) ? bb_b0 : bb_b + (l - 1) * 64;
        float acc = bb_[tid];
#pragma unroll 16
        for (int j = 0; j < 64; j++) acc += s_h[j] * bW[j * 64 + tid];
        ws[offB + (k * 8 + l) * 64 + tid] = acc;
    }
}

// one wave handles RPW rays; lane n = neuron n; no LDS, no barriers.
// Weight rows live in VGPRs (float4[16]); next layer prefetched during LN chain.
// launch_bounds(256,3): allow ~168 VGPRs so all 16 row loads stay in flight.
__global__ __launch_bounds__(256, 3) void forward_kernel(
    const float* __restrict__ rays,
    const float* __restrict__ ln_s0, const float* __restrict__ ln_b0,
    const float* __restrict__ ln_s, const float* __restrict__ ln_b,
    const float* __restrict__ rgb_W, const float* __restrict__ rgb_b,
    const float* __restrict__ ws, int offW, int offB,
    float* __restrict__ out, int K, int P)
{
    const int warp = threadIdx.x >> 6;
    const int lane = threadIdx.x & 63;
    const int total = K * P;
    const int r0 = (blockIdx.x * 4 + warp) * RPW;
    if (r0 >= total) return;            // whole-wave exit; no barriers anywhere
    const int k = r0 / P;               // P % 16 == 0 -> k uniform per wave

    // posenc for RPW rays
    float net0[RPW], net1[RPW];
#pragma unroll
    for (int q = 0; q < RPW; q++) {
        int r = r0 + q; if (r > total - 1) r = total - 1;
        float o0 = rays[r * 6 + 0], o1 = rays[r * 6 + 1], o2 = rays[r * 6 + 2];
        float d0 = rays[r * 6 + 3], d1 = rays[r * 6 + 4], d2 = rays[r * 6 + 5];
        float pl[6];
        pl[0] = d0; pl[1] = d1; pl[2] = d2;
        pl[3] = o1 * d2 - o2 * d1;
        pl[4] = o2 * d0 - o0 * d2;
        pl[5] = o0 * d1 - o1 * d0;
        net0[q] = posenc_elem(pl, lane);
        net1[q] = (lane + 64 < 126) ? posenc_elem(pl, lane + 64) : 0.0f;
    }

    const float* WL = ws + offW + (size_t)k * 7 * 4096;   // layers 1..7 base
    float acc[RPW];
    float4 w4[16];

    { // layer 0: n_in = 126 (padded 128); lane's row = W0 + lane*128
        const float4* row = (const float4*)(ws + (size_t)k * 8192 + lane * 128);
        float4 w4b[16];
#pragma unroll
        for (int j = 0; j < 16; j++) w4[j]  = row[j];        // m = 0..63
#pragma unroll
        for (int j = 0; j < 16; j++) w4b[j] = row[16 + j];   // m = 64..127 (pads zeroed)
        float bia = ws[offB + (k * 8 + 0) * 64 + lane];
        float pre[RPW];
#pragma unroll
        for (int q = 0; q < RPW; q++) pre[q] = bia;
#pragma unroll
        for (int m = 0; m < 64; m++) {
            float wm = ((const float*)w4)[m];
#pragma unroll
            for (int q = 0; q < RPW; q++) pre[q] += rl(net0[q], m) * wm;
        }
#pragma unroll
        for (int m = 0; m < 64; m++) {
            float wm = ((const float*)w4b)[m];
#pragma unroll
            for (int q = 0; q < RPW; q++) pre[q] += rl(net1[q], m) * wm;
        }
        // prefetch layer 1 weights BEFORE the LN chain (loads fly under shuffles)
        const float4* nrow = (const float4*)(WL + lane * 64);
#pragma unroll
        for (int j = 0; j < 16; j++) w4[j] = nrow[j];
        float s = ln_s0[lane], b = ln_b0[lane];
#pragma unroll
        for (int q = 0; q < RPW; q++) {
            float mu, rstd;
            ln_stats(pre[q], mu, rstd);
            acc[q] = fmaxf((pre[q] - mu) * rstd * s + b, 0.0f);
        }
    }

    // layers 1..7: n_in = 64; w4 holds layer l's row on entry
#pragma unroll 1
    for (int l = 1; l < 8; l++) {
        float na[RPW];
        float bia = ws[offB + (k * 8 + l) * 64 + lane];
#pragma unroll
        for (int q = 0; q < RPW; q++) na[q] = bia;
#pragma unroll
        for (int m = 0; m < 64; m++) {
            float wm = ((const float*)w4)[m];
#pragma unroll
            for (int q = 0; q < RPW; q++) na[q] += rl(acc[q], m) * wm;
        }
        // prefetch layer l+1 (clamped; l=7 re-fetches layer 7 row, harmless)
        {
            int lp = (l < 7) ? l : 6;
            const float4* nrow = (const float4*)(WL + (size_t)lp * 4096 + lane * 64);
#pragma unroll
            for (int j = 0; j < 16; j++) w4[j] = nrow[j];
        }
        float s = ln_s[(l - 1) * 64 + lane], b = ln_b[(l - 1) * 64 + lane];
#pragma unroll
        for (int q = 0; q < RPW; q++) {
            float mu, rstd;
            ln_stats(na[q], mu, rstd);
            acc[q] = fmaxf((na[q] - mu) * rstd * s + b, 0.0f);
        }
    }

    // rgb head: rgb_W is (64,3) row-major
    float w0 = rgb_W[lane * 3 + 0], w1 = rgb_W[lane * 3 + 1], w2 = rgb_W[lane * 3 + 2];
    float b0 = rgb_b[0], b1 = rgb_b[1], b2 = rgb_b[2];
#pragma unroll
    for (int q = 0; q < RPW; q++) {
        float c0 = wave_sum64(acc[q] * w0);
        float c1 = wave_sum64(acc[q] * w1);
        float c2 = wave_sum64(acc[q] * w2);
        if (lane == 0 && r0 + q < total) {
            out[(r0 + q) * 3 + 0] = 1.0f / (1.0f + expf(-(c0 + b0)));
            out[(r0 + q) * 3 + 1] = 1.0f / (1.0f + expf(-(c1 + b1)));
            out[(r0 + q) * 3 + 2] = 1.0f / (1.0f + expf(-(c2 + b2)));
        }
    }
}

extern "C" void kernel_launch(void* const* d_in, const int* in_sizes, int n_in,
                              void* d_out, int out_size, void* d_ws, size_t ws_size,
                              hipStream_t stream) {
    const float* rays    = (const float*)d_in[0];
    const float* latent  = (const float*)d_in[1];
    const float* tok_emb = (const float*)d_in[2];
    const float* h_W0    = (const float*)d_in[3];
    const float* h_b0    = (const float*)d_in[4];
    const float* h_ln_s0 = (const float*)d_in[5];
    const float* h_ln_b0 = (const float*)d_in[6];
    const float* w_W0    = (const float*)d_in[7];
    const float* w_b0    = (const float*)d_in[8];
    const float* bb_W0   = (const float*)d_in[9];
    const float* bb_b0   = (const float*)d_in[10];
    const float* ln_s0   = (const float*)d_in[11];
    const float* ln_b0   = (const float*)d_in[12];
    const float* h_W     = (const float*)d_in[13];
    const float* h_b     = (const float*)d_in[14];
    const float* h_ln_s  = (const float*)d_in[15];
    const float* h_ln_b  = (const float*)d_in[16];
    const float* w_W     = (const float*)d_in[17];
    const float* w_b     = (const float*)d_in[18];
    const float* bb_W    = (const float*)d_in[19];
    const float* bb_b    = (const float*)d_in[20];
    const float* ln_s    = (const float*)d_in[21];
    const float* ln_b    = (const float*)d_in[22];
    const float* rgb_W   = (const float*)d_in[23];
    const float* rgb_b   = (const float*)d_in[24];
    float* out = (float*)d_out;

    const int K = in_sizes[1] / (8 * 64);      // latent_tokens (K,8,64)
    const int P = in_sizes[0] / (6 * K);       // rays (K,P,6)
    const int offW = K * 8192;                 // f32 elements (W0 rows padded to 128)
    const int offB = offW + K * 7 * 4096;

    float* ws = (float*)d_ws;

    dim3 pgrid(32, 8, K);
    precompute_kernel<<<pgrid, 128, 0, stream>>>(
        latent, tok_emb, h_W0, h_b0, h_ln_s0, h_ln_b0, w_W0, w_b0, bb_W0, bb_b0,
        h_W, h_b, h_ln_s, h_ln_b, w_W, w_b, bb_W, bb_b, ws, offW, offB);

    const int total = K * P;
    const int rays_per_block = 4 * RPW;        // 4 waves * RPW rays
    const int blocks = (total + rays_per_block - 1) / rays_per_block;
    forward_kernel<<<blocks, 256, 0, stream>>>(
        rays, ln_s0, ln_b0, ln_s, ln_b, rgb_W, rgb_b,
        ws, offW, offB, out, K, P);
}